// Round 9
// baseline (350.179 us; speedup 1.0000x reference)
//
#include <hip/hip_runtime.h>

// GraphConv x3 on MI355X. R9: mega-kernel (edge fill + input dropout + weight
// pack + mask bit-pack, self-detecting dtypes via wave ballot — kills R0's
// serial 1-thread detect ~50us) + layer epilogue reads 800KB bitmask instead
// of 25.6MB int32 mask. 5 dispatches: memset, mega, layer x3.

#define C128 128
#define CAPS 96     // records per (segment, 16-dst bucket); mean 32, +11 sigma
#define CAPN 64     // records per node; mean 16, ~+12 sigma
#define NSEG 8

typedef short s16x8 __attribute__((ext_vector_type(8)));
typedef float f32x4 __attribute__((ext_vector_type(4)));

__device__ __forceinline__ ushort f2bf(float f) {        // RNE fp32->bf16
  unsigned u = __builtin_bit_cast(unsigned, f);
  u = (u + 0x7FFFu + ((u >> 16) & 1u)) >> 16;
  return (ushort)u;
}
__device__ __forceinline__ float bflo(unsigned v) {
  return __builtin_bit_cast(float, v << 16);
}
__device__ __forceinline__ float bfhi(unsigned v) {
  return __builtin_bit_cast(float, v & 0xFFFF0000u);
}
__device__ __forceinline__ unsigned pack2(float lo, float hi) {
  return (unsigned)f2bf(lo) | ((unsigned)f2bf(hi) << 16);
}

// Wave-parallel dtype detection (all lanes agree; 256B region is L1/L2-hot).
__device__ __forceinline__ int detect_e64(const int* __restrict__ eidx) {
  int lane = threadIdx.x & 63;
  return __ballot(eidx[2 * lane + 1] != 0) == 0ull;   // high words all 0
}
__device__ __forceinline__ int detect_m32(const int* __restrict__ mask) {
  int lane = threadIdx.x & 63;
  return __ballot(((unsigned)mask[lane]) > 1u) == 0ull; // words all in {0,1}
}

// ---------------------------------------------------------------------------
// mega: block-partitioned fused prep.
//  [0, fillG)                : edge -> (seg=blk&7, bucket=dst>>4) records
//  [fillG, +mpG)             : drop1 -> mbits1 (1 bit/elem)
//  [.., +mpG)                : drop2 -> mbits2
//  [.., +dropG)              : x * drop0 -> bf16 hdA
//  [.., +wpG)                : 6 weight mats -> MFMA-fragment-ordered Wpack
// ---------------------------------------------------------------------------
__global__ __launch_bounds__(256) void mega_kernel(
    const float* __restrict__ x, const int* __restrict__ eidx,
    const float* __restrict__ Wr0, const float* __restrict__ Wt0,
    const float* __restrict__ Wr1, const float* __restrict__ Wt1,
    const float* __restrict__ Wr2, const float* __restrict__ Wt2,
    const void* __restrict__ drop0, const void* __restrict__ drop1,
    const void* __restrict__ drop2,
    ushort* __restrict__ Wpack, int* __restrict__ cnt,
    unsigned* __restrict__ csrB, ushort* __restrict__ hdA,
    unsigned* __restrict__ mbits1, unsigned* __restrict__ mbits2,
    int E, int N, int nbuck16,
    int fillG, int mpG, int dropG, int wpG) {
  const int tid = threadIdx.x;
  int bi = blockIdx.x;

  if (bi < fillG) {                       // ---- edge fill ----
    int e = bi * 256 + tid;
    if (e >= E) return;
    int e64 = detect_e64(eidx);
    int seg = bi & (NSEG - 1);
    int src, dst;
    if (e64) { src = eidx[2 * e]; dst = eidx[2 * E + 2 * e]; }
    else     { src = eidx[e];     dst = eidx[E + e]; }
    int b = dst >> 4, dl = dst & 15;
    int cell = seg * nbuck16 + b;
    int pos = atomicAdd(&cnt[cell], 1);
    if (pos < CAPS)
      csrB[(size_t)cell * CAPS + pos] = (unsigned)src | ((unsigned)dl << 26);
    return;
  }
  bi -= fillG;

  if (bi < 2 * mpG) {                     // ---- mask bit-pack ----
    const void* mk = (bi < mpG) ? drop1 : drop2;
    unsigned* out = (bi < mpG) ? mbits1 : mbits2;
    int wi = (bi % mpG) * 256 + tid;
    int nwords = (N * C128) / 32;
    if (wi >= nwords) return;
    int m32 = detect_m32((const int*)mk);
    unsigned bits = 0;
    if (m32) {
      const uint4* p = (const uint4*)((const int*)mk + (size_t)wi * 32);
#pragma unroll
      for (int g = 0; g < 8; ++g) {
        uint4 v = p[g];
        bits |= (v.x ? 1u : 0u) << (g * 4 + 0);
        bits |= (v.y ? 1u : 0u) << (g * 4 + 1);
        bits |= (v.z ? 1u : 0u) << (g * 4 + 2);
        bits |= (v.w ? 1u : 0u) << (g * 4 + 3);
      }
    } else {
      const uint4* p = (const uint4*)((const unsigned char*)mk + (size_t)wi * 32);
#pragma unroll
      for (int h = 0; h < 2; ++h) {
        uint4 v = p[h];
        unsigned ws[4] = {v.x, v.y, v.z, v.w};
#pragma unroll
        for (int g = 0; g < 4; ++g) {
          unsigned u = ws[g];
          int base = h * 16 + g * 4;
          bits |= ((u & 0x000000FFu) ? 1u : 0u) << (base + 0);
          bits |= ((u & 0x0000FF00u) ? 1u : 0u) << (base + 1);
          bits |= ((u & 0x00FF0000u) ? 1u : 0u) << (base + 2);
          bits |= ((u & 0xFF000000u) ? 1u : 0u) << (base + 3);
        }
      }
    }
    out[wi] = bits;
    return;
  }
  bi -= 2 * mpG;

  if (bi < dropG) {                       // ---- input dropout ----
    int i = bi * 256 + tid;
    int n4 = (N * C128) / 4;
    if (i >= n4) return;
    int m32 = detect_m32((const int*)drop0);
    float4 v = ((const float4*)x)[i];
    int k0, k1, k2, k3;
    if (m32) {
      int4 m = ((const int4*)drop0)[i];
      k0 = m.x; k1 = m.y; k2 = m.z; k3 = m.w;
    } else {
      uchar4 m = ((const uchar4*)drop0)[i];
      k0 = m.x; k1 = m.y; k2 = m.z; k3 = m.w;
    }
    ushort4 r;
    r.x = k0 ? f2bf(v.x * 2.5f) : (ushort)0;
    r.y = k1 ? f2bf(v.y * 2.5f) : (ushort)0;
    r.z = k2 ? f2bf(v.z * 2.5f) : (ushort)0;
    r.w = k3 ? f2bf(v.w * 2.5f) : (ushort)0;
    ((ushort4*)hdA)[i] = r;
    return;
  }
  bi -= dropG;

  {                                       // ---- weight pack ----
    int t = bi * 256 + tid;
    if (t >= 3 * 32768) return;
    int L = t >> 15;
    int r = t & 32767;
    int c = r >> 12;
    int nt = (r >> 9) & 7;
    int lane = (r >> 3) & 63;
    int j = r & 7;
    int o = nt * 16 + (lane & 15);
    int k = (c & 3) * 32 + (lane >> 4) * 8 + j;
    const float* src;
    if (L == 0)      src = (c < 4) ? Wr0 : Wt0;
    else if (L == 1) src = (c < 4) ? Wr1 : Wt1;
    else             src = (c < 4) ? Wr2 : Wt2;
    Wpack[t] = f2bf(src[o * C128 + k]);
  }
}

// ---------------------------------------------------------------------------
// Fused layer: block = 16 nodes = one sub-bucket (blockIdx).
//  0) prefetch root-half A frags, bias, epilogue mask bits.
//  1) bin: 8 groups x 32 threads scan the 8 XCD segments concurrently.
//  2) gather: wave w -> nodes 4w..4w+3, unroll 2 (8 wave-loads in flight),
//     xor-reduce, deposit bf16 rows into 16x136 LDS tile.
//  3) MFMA: wave w -> cols {2w,2w+1}; agg half from LDS, root from regs,
//     B frags from Wpack (L2-hot).
//  4) epilogue: mode=1 ReLU + bit-packed dropout -> bf16; mode=0 -> fp32.
// ---------------------------------------------------------------------------
__global__ __launch_bounds__(256, 4) void layer_kernel(const ushort* __restrict__ hd,
                                                       const int* __restrict__ cnt,
                                                       const unsigned* __restrict__ csrB,
                                                       const ushort* __restrict__ Wpack,
                                                       const float* __restrict__ bias,
                                                       const unsigned* __restrict__ mbits,
                                                       void* __restrict__ outp,
                                                       int mode, int N, int nbuck16) {
  __shared__ int lists[16][CAPN];
  __shared__ int lcnt[16];
  __shared__ ushort As[16][136];   // 16 node rows, pad 8 (16B-aligned rows)

  const int b16 = blockIdx.x;
  const int tid = threadIdx.x;
  const int wave = tid >> 6, lane = tid & 63;
  const int quad = lane >> 4, l16 = lane & 15, co = l16 * 8;
  const int node0 = b16 * 16;

  // ---- 0) prefetches ----
  int prow = node0 + l16;
  if (prow >= N) prow = N - 1;
  const ushort* hrow = hd + (size_t)prow * C128 + quad * 8;
  s16x8 aroot[4];
#pragma unroll
  for (int c = 0; c < 4; ++c) aroot[c] = *(const s16x8*)(hrow + c * 32);
  float bv[2];
#pragma unroll
  for (int j = 0; j < 2; ++j) bv[j] = bias[(wave * 2 + j) * 16 + l16];

  unsigned mw[4];
  if (mode) {
#pragma unroll
    for (int r = 0; r < 4; ++r) {
      int node = node0 + quad * 4 + r;
      if (node >= N) node = N - 1;
      mw[r] = mbits[(size_t)node * 4 + wave];   // bits j*16+l16 for j=0,1
    }
  }

  // ---- 1) bin (8 segments concurrently) ----
  if (tid < 16) lcnt[tid] = 0;
  __syncthreads();
  {
    const int g = tid >> 5;          // segment 0..7
    const int gt = tid & 31;
    const int cell = g * nbuck16 + b16;
    int cs = cnt[cell];
    if (cs > CAPS) cs = CAPS;
    const unsigned* segp = csrB + (size_t)cell * CAPS;
    for (int i = gt; i < cs; i += 32) {
      unsigned r = segp[i];
      int dl = (int)(r >> 26);
      int pos = atomicAdd(&lcnt[dl], 1);
      if (pos < CAPN) lists[dl][pos] = (int)(r & 0x3FFFFFFu);
    }
  }
  __syncthreads();

  // ---- 2) gather: 4 nodes simultaneously, unroll 2 ----
  const ushort* base = hd + co;
  const int nb0 = wave * 4;
  int dcnt[4];
#pragma unroll
  for (int t = 0; t < 4; ++t) {
    int d = lcnt[nb0 + t];
    dcnt[t] = d > CAPN ? CAPN : d;
  }
  float ag[4][8];
#pragma unroll
  for (int t = 0; t < 4; ++t)
#pragma unroll
    for (int i = 0; i < 8; ++i) ag[t][i] = 0.f;

  int m = dcnt[0];
  if (dcnt[1] > m) m = dcnt[1];
  if (dcnt[2] > m) m = dcnt[2];
  if (dcnt[3] > m) m = dcnt[3];

  for (int e = quad; e < m; e += 8) {
    int e2 = e + 4;
#pragma unroll
    for (int t = 0; t < 4; ++t) {
      if (e < dcnt[t]) {
        uint4 v = *(const uint4*)(base + (size_t)lists[nb0 + t][e] * C128);
        ag[t][0] += bflo(v.x); ag[t][1] += bfhi(v.x);
        ag[t][2] += bflo(v.y); ag[t][3] += bfhi(v.y);
        ag[t][4] += bflo(v.z); ag[t][5] += bfhi(v.z);
        ag[t][6] += bflo(v.w); ag[t][7] += bfhi(v.w);
      }
    }
#pragma unroll
    for (int t = 0; t < 4; ++t) {
      if (e2 < dcnt[t]) {
        uint4 v = *(const uint4*)(base + (size_t)lists[nb0 + t][e2] * C128);
        ag[t][0] += bflo(v.x); ag[t][1] += bfhi(v.x);
        ag[t][2] += bflo(v.y); ag[t][3] += bfhi(v.y);
        ag[t][4] += bflo(v.z); ag[t][5] += bfhi(v.z);
        ag[t][6] += bflo(v.w); ag[t][7] += bfhi(v.w);
      }
    }
  }
#pragma unroll
  for (int t = 0; t < 4; ++t) {
#pragma unroll
    for (int i = 0; i < 8; ++i) {
      float v = ag[t][i];
      v += __shfl_xor(v, 16, 64);
      v += __shfl_xor(v, 32, 64);
      ag[t][i] = v;
    }
    if (quad == 0) {
      uint4 p;
      p.x = pack2(ag[t][0], ag[t][1]);
      p.y = pack2(ag[t][2], ag[t][3]);
      p.z = pack2(ag[t][4], ag[t][5]);
      p.w = pack2(ag[t][6], ag[t][7]);
      *(uint4*)&As[nb0 + t][co] = p;
    }
  }
  __syncthreads();

  // ---- 3) MFMA: wave handles nt = 2*wave, 2*wave+1 over all 16 rows ----
  f32x4 acc[2];
  acc[0] = (f32x4)0.f;
  acc[1] = (f32x4)0.f;
  const ushort* wp = Wpack + lane * 8;
#pragma unroll
  for (int c = 0; c < 8; ++c) {
    s16x8 afr;
    if (c < 4) afr = *(const s16x8*)&As[l16][c * 32 + quad * 8];
    else       afr = aroot[c - 4];
#pragma unroll
    for (int j = 0; j < 2; ++j) {
      int nt = wave * 2 + j;
      s16x8 bfr = *(const s16x8*)(wp + (c * 8 + nt) * 512);
      acc[j] = __builtin_amdgcn_mfma_f32_16x16x32_bf16(afr, bfr, acc[j], 0, 0, 0);
    }
  }

  // ---- 4) epilogue. C/D layout: col = lane&15, row = quad*4 + reg ----
  if (mode) {
    ushort* ob = (ushort*)outp;
#pragma unroll
    for (int j = 0; j < 2; ++j) {
      int o = (wave * 2 + j) * 16 + l16;
#pragma unroll
      for (int r = 0; r < 4; ++r) {
        int node = node0 + quad * 4 + r;
        if (node >= N) continue;
        float v = fmaxf(acc[j][r] + bv[j], 0.f);
        int keep = (mw[r] >> (j * 16 + l16)) & 1;
        ob[(size_t)node * C128 + o] = keep ? f2bf(v * 2.5f) : (ushort)0;
      }
    }
  } else {
    float* of = (float*)outp;
#pragma unroll
    for (int j = 0; j < 2; ++j) {
      int o = (wave * 2 + j) * 16 + l16;
#pragma unroll
      for (int r = 0; r < 4; ++r) {
        int node = node0 + quad * 4 + r;
        if (node >= N) continue;
        of[(size_t)node * C128 + o] = acc[j][r] + bv[j];
      }
    }
  }
}

// ---------------------------------------------------------------------------
extern "C" void kernel_launch(void* const* d_in, const int* in_sizes, int n_in,
                              void* d_out, int out_size, void* d_ws, size_t ws_size,
                              hipStream_t stream) {
  const float* x      = (const float*)d_in[0];
  const int*   eidx   = (const int*)d_in[1];
  const float* Wrel0  = (const float*)d_in[2];
  const float* Wroot0 = (const float*)d_in[3];
  const float* b0     = (const float*)d_in[4];
  const float* Wrel1  = (const float*)d_in[5];
  const float* Wroot1 = (const float*)d_in[6];
  const float* b1     = (const float*)d_in[7];
  const float* Wrel2  = (const float*)d_in[8];
  const float* Wroot2 = (const float*)d_in[9];
  const float* b2     = (const float*)d_in[10];
  const void*  drop0  = d_in[11];
  const void*  drop1  = d_in[12];
  const void*  drop2  = d_in[13];

  const int N       = in_sizes[0] / C128;
  const int E       = in_sizes[1] / 2;
  const int NC      = N * C128;
  const int nbuck16 = (N + 15) / 16;
  const int nCells  = NSEG * nbuck16;
  const int nwords  = NC / 32;

  char*     ws     = (char*)d_ws;
  ushort*   Wpack  = (ushort*)ws;                          // 3*32768 bf16
  int*      cnt    = (int*)(Wpack + 3 * 32768);            // nCells ints
  unsigned* csrB   = (unsigned*)(cnt + nCells);            // nCells*CAPS recs
  unsigned* mbits1 = (unsigned*)(csrB + (size_t)nCells * CAPS);  // nwords
  unsigned* mbits2 = mbits1 + nwords;
  ushort*   hdA    = (ushort*)(mbits2 + nwords);
  ushort*   hdB    = hdA + NC;

  const ushort* Wp0 = Wpack;
  const ushort* Wp1 = Wpack + 32768;
  const ushort* Wp2 = Wpack + 2 * 32768;

  hipMemsetAsync(cnt, 0, (size_t)nCells * sizeof(int), stream);

  const int fillG = (E + 255) / 256;
  const int mpG   = (nwords + 255) / 256;
  const int dropG = (NC / 4 + 255) / 256;
  const int wpG   = (3 * 32768 + 255) / 256;
  const int megaG = fillG + 2 * mpG + dropG + wpG;

  mega_kernel<<<megaG, 256, 0, stream>>>(
      x, eidx, Wrel0, Wroot0, Wrel1, Wroot1, Wrel2, Wroot2,
      drop0, drop1, drop2,
      Wpack, cnt, csrB, hdA, mbits1, mbits2,
      E, N, nbuck16, fillG, mpG, dropG, wpG);

  // layer 0: hdA -> hdB (relu + drop1 fused)
  layer_kernel<<<nbuck16, 256, 0, stream>>>(hdA, cnt, csrB, Wp0, b0, mbits1,
                                            hdB, 1, N, nbuck16);
  // layer 1: hdB -> hdA (relu + drop2 fused)
  layer_kernel<<<nbuck16, 256, 0, stream>>>(hdB, cnt, csrB, Wp1, b1, mbits2,
                                            hdA, 1, N, nbuck16);
  // layer 2: hdA -> d_out (fp32)
  layer_kernel<<<nbuck16, 256, 0, stream>>>(hdA, cnt, csrB, Wp2, b2, nullptr,
                                            d_out, 0, N, nbuck16);
}